// Round 4
// baseline (106.433 us; speedup 1.0000x reference)
//
#include <hip/hip_runtime.h>

#define NC      16
#define HW      (512 * 512)
#define NB      8
#define BPB     128                       // blocks per batch
#define NBLK    (NB * BPB)                // 1024 total blocks
#define THREADS 256
#define CHUNK   (HW / BPB)                // 2048 pixels per block
#define SMOOTH  1e-5f

// Partials in d_ws, SoA: P[v * NBLK + blk], v in [0,34):
//   v = 0..15  : inter[c]   (batch b = blk / BPB)
//   v = 16..31 : denom[c]
//   v = 32     : ce partial
//   v = 33     : pen partial
// Every slot overwritten every launch -> no zeroing, no atomics.
__global__ __launch_bounds__(THREADS) void domino_main(
    const float* __restrict__ logits,   // [B, C, H, W]
    const int*   __restrict__ tgt,      // [B, H, W]
    const float* __restrict__ penalty,  // [C, C] row = target class
    float*       __restrict__ P)
{
    __shared__ float pen_t[NC * NC];    // transposed: pen_t[c*NC + t] = penalty[t*NC + c]
    __shared__ float red[4][34];

    const int tid = threadIdx.x;
    const int b   = blockIdx.x / BPB;
    const int blk = blockIdx.x % BPB;

    if (tid < NC * NC) {
        const int r = tid / NC, c = tid % NC;
        pen_t[c * NC + r] = penalty[tid];
    }
    __syncthreads();

    float inter_acc[NC], denom_acc[NC];
#pragma unroll
    for (int c = 0; c < NC; ++c) { inter_acc[c] = 0.f; denom_acc[c] = 0.f; }
    float ce_acc = 0.f, pen_acc = 0.f;

    const float* ob = logits + (size_t)b * NC * HW;
    const int*   tb = tgt    + (size_t)b * HW;

    // ---- explicit 2-deep prefetch: statically named buffers only (rule #20) ----
#define LOADX(X, T, K) do {                                                  \
        const int pix = (blk * (CHUNK / 2) + (K) * THREADS + tid) * 2;       \
        _Pragma("unroll")                                                    \
        for (int c = 0; c < NC; ++c)                                         \
            X[c] = *(const float2*)(ob + (size_t)c * HW + pix);              \
        T = *(const int2*)(tb + pix);                                        \
    } while (0)

    // One pixel = component F of the float2, target TT.
    // x[t] via 4-level mux tree (compile-time indices only).
#define PROC(X, F, TT) do {                                                  \
        const int t = (TT);                                                  \
        const bool t0 = t & 1, t1 = t & 2, t2 = t & 4, t3 = t & 8;           \
        float m = -3.402823466e+38f;                                         \
        _Pragma("unroll")                                                    \
        for (int c = 0; c < NC; ++c) m = fmaxf(m, X[c].F);                   \
        float s = 0.f;                                                       \
        _Pragma("unroll")                                                    \
        for (int c = 0; c < NC; ++c) s += __expf(X[c].F - m);                \
        float z[8];                                                          \
        _Pragma("unroll")                                                    \
        for (int i = 0; i < 8; ++i) z[i] = t0 ? X[2*i+1].F : X[2*i].F;       \
        _Pragma("unroll")                                                    \
        for (int i = 0; i < 4; ++i) z[i] = t1 ? z[2*i+1] : z[2*i];           \
        z[0] = t2 ? z[2] : z[0];                                             \
        z[1] = t2 ? z[3] : z[1];                                             \
        const float xt = t3 ? z[1] : z[0];                                   \
        const float inv = 1.0f / s;                                          \
        ce_acc += (__logf(s) + m) - xt;                                      \
        float pdot = 0.f;                                                    \
        _Pragma("unroll")                                                    \
        for (int c = 0; c < NC; ++c) {                                       \
            const float p = __expf(X[c].F - m) * inv;                        \
            denom_acc[c] += p + ((t == c) ? 1.f : 0.f);                      \
            inter_acc[c] += (t == c) ? p : 0.f;                              \
            pdot += pen_t[c * NC + t] * p;                                   \
        }                                                                    \
        pen_acc += pdot;                                                     \
    } while (0)

#define PROC2(X, T) do { PROC(X, x, T.x); PROC(X, y, T.y); } while (0)

    float2 xA[NC], xB[NC];
    int2 tA, tB;
    LOADX(xA, tA, 0);
    LOADX(xB, tB, 1);
    PROC2(xA, tA);
    LOADX(xA, tA, 2);
    PROC2(xB, tB);
    LOADX(xB, tB, 3);
    PROC2(xA, tA);
    PROC2(xB, tB);
#undef PROC2
#undef PROC
#undef LOADX

    // Intra-wave butterfly reductions (64 lanes).
#pragma unroll
    for (int c = 0; c < NC; ++c) {
#pragma unroll
        for (int off = 32; off; off >>= 1) {
            inter_acc[c] += __shfl_xor(inter_acc[c], off);
            denom_acc[c] += __shfl_xor(denom_acc[c], off);
        }
    }
#pragma unroll
    for (int off = 32; off; off >>= 1) {
        ce_acc  += __shfl_xor(ce_acc,  off);
        pen_acc += __shfl_xor(pen_acc, off);
    }

    const int lane = tid & 63, wid = tid >> 6;
    if (lane == 0) {
#pragma unroll
        for (int c = 0; c < NC; ++c) {
            red[wid][c]      = inter_acc[c];
            red[wid][NC + c] = denom_acc[c];
        }
        red[wid][32] = ce_acc;
        red[wid][33] = pen_acc;
    }
    __syncthreads();

    if (tid < 34) {
        const float v = red[0][tid] + red[1][tid] + red[2][tid] + red[3][tid];
        P[tid * NBLK + blockIdx.x] = v;
    }
}

// One block, 1024 threads: 8 threads per (c,b) dice bin (each sums 16 of the
// 128 per-batch partials), plus full-width ce/pen reduction. Single pass.
__global__ __launch_bounds__(1024) void domino_final(
    const float* __restrict__ P, float* __restrict__ out)
{
    __shared__ float dice_l[128], ce_l[16], pen_l[16];

    const int tid = threadIdx.x;
    const int bin = tid >> 3, j = tid & 7;   // bin in [0,128)
    const int c = bin >> 3, b = bin & 7;

    const float4* ip = (const float4*)(P + (size_t)c        * NBLK + b * BPB) + j * 4;
    const float4* dp = (const float4*)(P + (size_t)(NC + c) * NBLK + b * BPB) + j * 4;
    float inter = 0.f, denom = 0.f;
#pragma unroll
    for (int k = 0; k < 4; ++k) {
        const float4 a = ip[k]; inter += a.x + a.y + a.z + a.w;
        const float4 d = dp[k]; denom += d.x + d.y + d.z + d.w;
    }
#pragma unroll
    for (int off = 4; off; off >>= 1) {      // reduce the 8-thread group
        inter += __shfl_xor(inter, off);
        denom += __shfl_xor(denom, off);
    }
    if (j == 0)
        dice_l[bin] = 1.0f - (2.0f * inter + SMOOTH) / (denom + SMOOTH);

    float ce  = P[32 * NBLK + tid];          // NBLK == 1024 == blockDim
    float pen = P[33 * NBLK + tid];
#pragma unroll
    for (int off = 32; off; off >>= 1) {
        ce  += __shfl_xor(ce,  off);
        pen += __shfl_xor(pen, off);
    }
    const int lane = tid & 63, wid = tid >> 6;
    if (lane == 0) { ce_l[wid] = ce; pen_l[wid] = pen; }
    __syncthreads();

    if (tid < 64) {
        float d = dice_l[tid] + dice_l[tid + 64];
#pragma unroll
        for (int off = 32; off; off >>= 1) d += __shfl_xor(d, off);
        if (tid == 0) {
            float ces = 0.f, pens = 0.f;
#pragma unroll
            for (int i = 0; i < 16; ++i) { ces += ce_l[i]; pens += pen_l[i]; }
            out[0] = ces  * (1.0f / (8.0f * 262144.0f))
                   + d    * (1.0f / 128.0f)
                   + pens * (1.0f / 8.0f);
        }
    }
}

extern "C" void kernel_launch(void* const* d_in, const int* in_sizes, int n_in,
                              void* d_out, int out_size, void* d_ws, size_t ws_size,
                              hipStream_t stream)
{
    const float* logits = (const float*)d_in[0];   // [8,16,512,512] f32
    const int*   tgt    = (const int*)d_in[1];     // [8,1,512,512] int32
    const float* pen    = (const float*)d_in[2];   // [16,16] f32
    float*       P      = (float*)d_ws;
    float*       out    = (float*)d_out;

    domino_main<<<NBLK, THREADS, 0, stream>>>(logits, tgt, pen, P);
    domino_final<<<1, 1024, 0, stream>>>(P, out);
}

// Round 5
// 39.975 us; speedup vs baseline: 2.6625x; 2.6625x over previous
//
#include <hip/hip_runtime.h>

#define NC      16
#define HW      (512 * 512)
#define NB      8
#define BPB     128                       // blocks per batch
#define NBLK    (NB * BPB)                // 1024 total blocks
#define THREADS 256
#define CHUNK   (HW / BPB)                // 2048 pixels per block
#define VITERS  (CHUNK / (THREADS * 4))   // 2 float4-iterations per thread
#define SMOOTH  1e-5f

// Partials in d_ws, SoA: P[v * NBLK + blk], v in [0,34):
//   v = 0..15  : inter[c]   (batch b = blk / BPB)
//   v = 16..31 : denom[c]
//   v = 32     : ce partial
//   v = 33     : pen partial
// Every slot overwritten every launch -> no zeroing, no atomics.
//
// Register discipline (learned r2/r4): ONE x buffer, no e[16] cache, no mux
// tree, no manual prefetch. float4 x[16] = 64 VGPR + 34 acc + temps ~= 120.
// Falsifier: LDS_Block_Size > 2048 or WRITE_SIZE >> 1 MB => spilled, revert.
__global__ __launch_bounds__(THREADS) void domino_main(
    const float* __restrict__ logits,   // [B, C, H, W]
    const int*   __restrict__ tgt,      // [B, H, W]
    const float* __restrict__ penalty,  // [C, C] row = target class
    float*       __restrict__ P)
{
    __shared__ float pen_t[NC * NC];    // transposed: pen_t[c*NC + t] = penalty[t*NC + c]
    __shared__ float red[4][34];

    const int tid = threadIdx.x;
    const int b   = blockIdx.x / BPB;
    const int blk = blockIdx.x % BPB;

    if (tid < NC * NC) {
        const int r = tid / NC, c = tid % NC;
        pen_t[c * NC + r] = penalty[tid];
    }
    __syncthreads();

    float inter_acc[NC], denom_acc[NC];
#pragma unroll
    for (int c = 0; c < NC; ++c) { inter_acc[c] = 0.f; denom_acc[c] = 0.f; }
    float ce_acc = 0.f, pen_acc = 0.f;

    const float* ob = logits + (size_t)b * NC * HW;
    const int*   tb = tgt    + (size_t)b * HW;

#pragma unroll
    for (int k = 0; k < VITERS; ++k) {
        const int g   = blk * (CHUNK / 4) + k * THREADS + tid;  // float4 group index
        const int pix = g * 4;

        float4 x[NC];
#pragma unroll
        for (int c = 0; c < NC; ++c)
            x[c] = *(const float4*)(ob + (size_t)c * HW + pix);
        const int4 t4 = *(const int4*)(tb + pix);

        // One pixel = component F of the float4 group, target TT.
        // exp recomputed in the 2nd class pass (trans pipe is cheap) so no
        // e[16]; xt via 16 predicated selects (compile-time indices only).
#define PROC(F, TT) do {                                                    \
        const int t = (TT);                                                 \
        float m = -3.402823466e+38f;                                        \
        _Pragma("unroll")                                                   \
        for (int c = 0; c < NC; ++c) m = fmaxf(m, x[c].F);                  \
        float s = 0.f, xt = 0.f;                                            \
        _Pragma("unroll")                                                   \
        for (int c = 0; c < NC; ++c) {                                      \
            s  += __expf(x[c].F - m);                                       \
            xt += (t == c) ? x[c].F : 0.f;                                  \
        }                                                                   \
        const float inv = 1.0f / s;                                         \
        ce_acc += (__logf(s) + m) - xt;                                     \
        float pdot = 0.f;                                                   \
        _Pragma("unroll")                                                   \
        for (int c = 0; c < NC; ++c) {                                      \
            const float p = __expf(x[c].F - m) * inv;                       \
            denom_acc[c] += p + ((t == c) ? 1.f : 0.f);                     \
            inter_acc[c] += (t == c) ? p : 0.f;                             \
            pdot += pen_t[c * NC + t] * p;                                  \
        }                                                                   \
        pen_acc += pdot;                                                    \
    } while (0)

        PROC(x, t4.x);
        PROC(y, t4.y);
        PROC(z, t4.z);
        PROC(w, t4.w);
#undef PROC
    }

    // Intra-wave butterfly reductions (64 lanes).
#pragma unroll
    for (int c = 0; c < NC; ++c) {
#pragma unroll
        for (int off = 32; off; off >>= 1) {
            inter_acc[c] += __shfl_xor(inter_acc[c], off);
            denom_acc[c] += __shfl_xor(denom_acc[c], off);
        }
    }
#pragma unroll
    for (int off = 32; off; off >>= 1) {
        ce_acc  += __shfl_xor(ce_acc,  off);
        pen_acc += __shfl_xor(pen_acc, off);
    }

    const int lane = tid & 63, wid = tid >> 6;
    if (lane == 0) {
#pragma unroll
        for (int c = 0; c < NC; ++c) {
            red[wid][c]      = inter_acc[c];
            red[wid][NC + c] = denom_acc[c];
        }
        red[wid][32] = ce_acc;
        red[wid][33] = pen_acc;
    }
    __syncthreads();

    if (tid < 34) {
        const float v = red[0][tid] + red[1][tid] + red[2][tid] + red[3][tid];
        P[tid * NBLK + blockIdx.x] = v;
    }
}

// One block, 1024 threads: 8 threads per (c,b) dice bin (each sums 16 of the
// 128 per-batch partials), plus full-width ce/pen reduction. Single pass.
__global__ __launch_bounds__(1024) void domino_final(
    const float* __restrict__ P, float* __restrict__ out)
{
    __shared__ float dice_l[128], ce_l[16], pen_l[16];

    const int tid = threadIdx.x;
    const int bin = tid >> 3, j = tid & 7;   // bin in [0,128)
    const int c = bin >> 3, b = bin & 7;

    const float4* ip = (const float4*)(P + (size_t)c        * NBLK + b * BPB) + j * 4;
    const float4* dp = (const float4*)(P + (size_t)(NC + c) * NBLK + b * BPB) + j * 4;
    float inter = 0.f, denom = 0.f;
#pragma unroll
    for (int k = 0; k < 4; ++k) {
        const float4 a = ip[k]; inter += a.x + a.y + a.z + a.w;
        const float4 d = dp[k]; denom += d.x + d.y + d.z + d.w;
    }
#pragma unroll
    for (int off = 4; off; off >>= 1) {      // reduce the 8-thread group
        inter += __shfl_xor(inter, off);
        denom += __shfl_xor(denom, off);
    }
    if (j == 0)
        dice_l[bin] = 1.0f - (2.0f * inter + SMOOTH) / (denom + SMOOTH);

    float ce  = P[32 * NBLK + tid];          // NBLK == 1024 == blockDim
    float pen = P[33 * NBLK + tid];
#pragma unroll
    for (int off = 32; off; off >>= 1) {
        ce  += __shfl_xor(ce,  off);
        pen += __shfl_xor(pen, off);
    }
    const int lane = tid & 63, wid = tid >> 6;
    if (lane == 0) { ce_l[wid] = ce; pen_l[wid] = pen; }
    __syncthreads();

    if (tid < 64) {
        float d = dice_l[tid] + dice_l[tid + 64];
#pragma unroll
        for (int off = 32; off; off >>= 1) d += __shfl_xor(d, off);
        if (tid == 0) {
            float ces = 0.f, pens = 0.f;
#pragma unroll
            for (int i = 0; i < 16; ++i) { ces += ce_l[i]; pens += pen_l[i]; }
            out[0] = ces  * (1.0f / (8.0f * 262144.0f))
                   + d    * (1.0f / 128.0f)
                   + pens * (1.0f / 8.0f);
        }
    }
}

extern "C" void kernel_launch(void* const* d_in, const int* in_sizes, int n_in,
                              void* d_out, int out_size, void* d_ws, size_t ws_size,
                              hipStream_t stream)
{
    const float* logits = (const float*)d_in[0];   // [8,16,512,512] f32
    const int*   tgt    = (const int*)d_in[1];     // [8,1,512,512] int32
    const float* pen    = (const float*)d_in[2];   // [16,16] f32
    float*       P      = (float*)d_ws;
    float*       out    = (float*)d_out;

    domino_main<<<NBLK, THREADS, 0, stream>>>(logits, tgt, pen, P);
    domino_final<<<1, 1024, 0, stream>>>(P, out);
}